// Round 1
// baseline (280.141 us; speedup 1.0000x reference)
//
#include <hip/hip_runtime.h>

#define NEG_W 8.0f
#define EPS 1e-7f
#define TPB 256
#define VPT 4                 // 4 float4 + 4 int4 per thread
#define BLOCKS 8192           // 8192*256*4 float4 = 8,388,608 = N/4 exactly

typedef float f32x4 __attribute__((ext_vector_type(4)));
typedef int   i32x4 __attribute__((ext_vector_type(4)));

// Round 3: rocprof showed VGPR_Count STILL 20 with sched_barrier(0) -> the
// register allocator was recycling one load buffer, serializing the 8 loads
// (1-2 in flight instead of 8; kernel latency-bound at 2.8 TB/s delivered).
// Fix: empty asm with "+v" on all 8 vectors forces them simultaneously live
// in distinct VGPRs -- loads MUST all issue before the first consume.
__global__ __launch_bounds__(TPB) void bce_partial(
    const f32x4* __restrict__ out4, const i32x4* __restrict__ tgt4,
    float* __restrict__ partials) {
  const int base = blockIdx.x * (TPB * VPT) + threadIdx.x;

  f32x4 o0 = out4[base + 0 * TPB];
  f32x4 o1 = out4[base + 1 * TPB];
  f32x4 o2 = out4[base + 2 * TPB];
  f32x4 o3 = out4[base + 3 * TPB];
  i32x4 t0 = tgt4[base + 0 * TPB];
  i32x4 t1 = tgt4[base + 1 * TPB];
  i32x4 t2 = tgt4[base + 2 * TPB];
  i32x4 t3 = tgt4[base + 3 * TPB];
  // All 8 results pinned live at once: allocator cannot serialize the loads.
  asm volatile("" : "+v"(o0), "+v"(o1), "+v"(o2), "+v"(o3),
                    "+v"(t0), "+v"(t1), "+v"(t2), "+v"(t3));

  float acc0 = 0.0f, acc1 = 0.0f, acc2 = 0.0f, acc3 = 0.0f;
#define BCE_BODY(o, t)                                              \
  {                                                                 \
    float x0 = (t.x == 1) ? (o.x + EPS) : (1.0f - o.x + EPS);       \
    float w0 = (t.x == 1) ? 1.0f : NEG_W;                           \
    float x1 = (t.y == 1) ? (o.y + EPS) : (1.0f - o.y + EPS);       \
    float w1 = (t.y == 1) ? 1.0f : NEG_W;                           \
    float x2 = (t.z == 1) ? (o.z + EPS) : (1.0f - o.z + EPS);       \
    float w2 = (t.z == 1) ? 1.0f : NEG_W;                           \
    float x3 = (t.w == 1) ? (o.w + EPS) : (1.0f - o.w + EPS);       \
    float w3 = (t.w == 1) ? 1.0f : NEG_W;                           \
    acc0 = fmaf(w0, __logf(x0), acc0);                              \
    acc1 = fmaf(w1, __logf(x1), acc1);                              \
    acc2 = fmaf(w2, __logf(x2), acc2);                              \
    acc3 = fmaf(w3, __logf(x3), acc3);                              \
  }
  BCE_BODY(o0, t0)
  BCE_BODY(o1, t1)
  BCE_BODY(o2, t2)
  BCE_BODY(o3, t3)
#undef BCE_BODY

  float sum = -((acc0 + acc1) + (acc2 + acc3));

  // wave64 butterfly reduce
  for (int off = 32; off > 0; off >>= 1)
    sum += __shfl_down(sum, off, 64);

  __shared__ float wsum[TPB / 64];
  const int lane = threadIdx.x & 63;
  const int wid = threadIdx.x >> 6;
  if (lane == 0) wsum[wid] = sum;
  __syncthreads();
  if (threadIdx.x == 0) {
    float s = 0.0f;
    for (int w = 0; w < TPB / 64; ++w) s += wsum[w];
    partials[blockIdx.x] = s;
  }
}

// Kernel 2: single block reduces BLOCKS float partials in double, writes mean.
__global__ __launch_bounds__(TPB) void bce_finalize(
    const float* __restrict__ partials, float* __restrict__ out, int nblocks,
    double inv_n) {
  double s = 0.0;
  for (int i = threadIdx.x; i < nblocks; i += TPB) s += (double)partials[i];
  for (int off = 32; off > 0; off >>= 1)
    s += __shfl_down(s, off, 64);
  __shared__ double wsum[TPB / 64];
  const int lane = threadIdx.x & 63;
  const int wid = threadIdx.x >> 6;
  if (lane == 0) wsum[wid] = s;
  __syncthreads();
  if (threadIdx.x == 0) {
    double tot = 0.0;
    for (int w = 0; w < TPB / 64; ++w) tot += wsum[w];
    out[0] = (float)(tot * inv_n);
  }
}

extern "C" void kernel_launch(void* const* d_in, const int* in_sizes, int n_in,
                              void* d_out, int out_size, void* d_ws, size_t ws_size,
                              hipStream_t stream) {
  const f32x4* out4 = (const f32x4*)d_in[0];
  const i32x4* tgt4 = (const i32x4*)d_in[1];
  const int n = in_sizes[0];          // 33554432 = BLOCKS*TPB*VPT*4 exactly
  float* partials = (float*)d_ws;     // 8192 * 4 B = 32 KB scratch
  (void)n;

  bce_partial<<<BLOCKS, TPB, 0, stream>>>(out4, tgt4, partials);
  bce_finalize<<<1, TPB, 0, stream>>>(partials, (float*)d_out, BLOCKS,
                                      1.0 / (double)33554432);
}